// Round 1
// baseline (191.668 us; speedup 1.0000x reference)
//
#include <hip/hip_runtime.h>

// Problem constants (from reference setup_inputs)
constexpr int Bn  = 256;   // batch
constexpr int Nn  = 16;    // template children
constexpr int Mn  = 128;   // sequence length
constexpr int Vn  = 64;    // vocab
constexpr int Hn  = 128;   // hidden
constexpr int Kn  = 8;     // template rows
constexpr int NP1 = 17;    // N+1
constexpr int KN  = Kn * NP1; // 136

__global__ __launch_bounds__(256) void fused_template_pack(
    const float* __restrict__ dec,       // [B,N,M,V]
    const float* __restrict__ type_emb,  // [T,H]
    const float* __restrict__ w_sem,     // [15, K*(N+1), H]
    const float* __restrict__ b_sem,     // [15, K*(N+1)]
    const float* __restrict__ gumbel,    // [B,K,N+1]
    const int*   __restrict__ ttypes,    // [B]
    const int*   __restrict__ spans,     // [B]
    float*       __restrict__ out)       // [B,M,V]
{
    const int b    = blockIdx.x;
    const int tid  = threadIdx.x;
    const int lane = tid & 63;
    const int wave = tid >> 6;

    __shared__ float s_scores[KN];
    __shared__ int   s_sel[Kn];
    __shared__ int   s_len[Kn];
    __shared__ int   s_off[Kn];
    __shared__ int   s_eff[Kn];
    __shared__ int   s_total;

    const int t    = ttypes[b];
    const int span = spans[b];

    // ---- Phase 1: template selection (argmax_n of logits + gumbel) ----
    if (t != 20) {
        if (tid < KN) {
            const int n = tid % NP1;
            float score = -1e30f;
            if (n <= span) {
                const float4* wrow = (const float4*)(w_sem + ((size_t)(t - 9) * KN + tid) * Hn);
                const float4* erow = (const float4*)(type_emb + (size_t)t * Hn);
                float acc = 0.f;
                #pragma unroll
                for (int i = 0; i < Hn / 4; ++i) {
                    float4 wv = wrow[i];
                    float4 ev = erow[i];
                    acc += wv.x * ev.x + wv.y * ev.y + wv.z * ev.z + wv.w * ev.w;
                }
                score = acc + b_sem[(t - 9) * KN + tid] + gumbel[(size_t)b * KN + tid];
            }
            s_scores[tid] = score;
        }
        __syncthreads();
        if (tid < Kn) {
            int best = 0;
            float bv = s_scores[tid * NP1];
            #pragma unroll
            for (int n = 1; n < NP1; ++n) {
                float v = s_scores[tid * NP1 + n];
                if (v > bv) { bv = v; best = n; }   // first-max tie-break (strict >)
            }
            s_sel[tid] = best;
        }
    } else {
        // special start template: row 0 -> child 1, rows 1..7 -> pad
        if (tid < Kn) s_sel[tid] = (tid == 0) ? 1 : 0;
    }
    __syncthreads();

    // ---- Phase 2: per-template effective length ----
    // len[k] = max_m( m+1 if argmax_v dec[b, sel-1, m, :] != 0 else 0 ); 0 for pad
    for (int k = wave; k < Kn; k += 4) {
        const int s = s_sel[k];
        int local = 0;
        if (s > 0) {
            const float* row = dec + (((size_t)b * Nn + (s - 1)) * Mn) * Vn;
            #pragma unroll
            for (int half = 0; half < 2; ++half) {
                const int m = lane + half * 64;
                const float4* p = (const float4*)(row + (size_t)m * Vn);
                float bv = -__builtin_inff();
                int bidx = 0;
                #pragma unroll
                for (int j = 0; j < Vn / 4; ++j) {
                    float4 v4 = p[j];
                    if (v4.x > bv) { bv = v4.x; bidx = 4 * j + 0; }
                    if (v4.y > bv) { bv = v4.y; bidx = 4 * j + 1; }
                    if (v4.z > bv) { bv = v4.z; bidx = 4 * j + 2; }
                    if (v4.w > bv) { bv = v4.w; bidx = 4 * j + 3; }
                }
                if (bidx != 0) local = max(local, m + 1);
            }
        }
        // wave-level max reduction (64 lanes)
        #pragma unroll
        for (int d = 32; d > 0; d >>= 1)
            local = max(local, __shfl_xor(local, d, 64));
        if (lane == 0) s_len[k] = local;
    }
    __syncthreads();

    // ---- Phase 3: sequential packing offsets (scan over K=8) ----
    if (tid == 0) {
        int idx = 0;
        #pragma unroll
        for (int k = 0; k < Kn; ++k) {
            const int eff = min(s_len[k], Mn - idx);
            s_off[k] = idx;
            s_eff[k] = eff;
            idx += eff;
        }
        s_total = idx;
    }
    __syncthreads();

    // ---- Phase 4: copy packed rows ----
    float4* outb = (float4*)(out + (size_t)b * Mn * Vn);
    for (int k = 0; k < Kn; ++k) {
        const int eff = s_eff[k];
        if (eff == 0) continue;
        const float4* src =
            (const float4*)(dec + (((size_t)b * Nn + (s_sel[k] - 1)) * Mn) * Vn);
        float4* dst = outb + (size_t)s_off[k] * (Vn / 4);
        const int cnt = eff * (Vn / 4);
        for (int i = tid; i < cnt; i += 256) dst[i] = src[i];
    }

    // ---- Phase 5: zero-fill the tail rows ----
    const int total = s_total;
    const int zcnt  = (Mn - total) * (Vn / 4);
    float4* zdst = outb + (size_t)total * (Vn / 4);
    const float4 zero = make_float4(0.f, 0.f, 0.f, 0.f);
    for (int i = tid; i < zcnt; i += 256) zdst[i] = zero;
}

extern "C" void kernel_launch(void* const* d_in, const int* in_sizes, int n_in,
                              void* d_out, int out_size, void* d_ws, size_t ws_size,
                              hipStream_t stream) {
    const float* dec      = (const float*)d_in[0];
    const float* type_emb = (const float*)d_in[1];
    const float* w_sem    = (const float*)d_in[2];
    const float* b_sem    = (const float*)d_in[3];
    const float* gumbel   = (const float*)d_in[4];
    const int*   ttypes   = (const int*)d_in[5];
    const int*   spans    = (const int*)d_in[6];
    float* out = (float*)d_out;

    fused_template_pack<<<Bn, 256, 0, stream>>>(
        dec, type_emb, w_sem, b_sem, gumbel, ttypes, spans, out);
}